// Round 7
// baseline (279.960 us; speedup 1.0000x reference)
//
#include <hip/hip_runtime.h>
#include <hip/hip_bf16.h>
#include <hip/hip_cooperative_groups.h>
#include <math.h>

namespace cg = cooperative_groups;

// Problem constants: B=4, S=512, N=8 sensors, D=256, H=8 heads, hd=32, BN=B*N=32
#define B_   4
#define S_   512
#define N_   8
#define D_   256
#define H_   8
#define HD_  32
#define BN_  32
#define MTOT (BN_ * S_)   // 16384 rows in the folded (BN,S) space

typedef __attribute__((ext_vector_type(8))) short short8;    // 8 bf16 = 4 VGPRs (MFMA A/B frag)
typedef __attribute__((ext_vector_type(4))) short short4v;   // 4 bf16 = 8 B
typedef __attribute__((ext_vector_type(4))) float floatx4;   // MFMA C/D frag / fp32 vec IO

// exp2-domain score scale: 1/sqrt(32) * log2(e), folded into the Q projection
#define QSCALE 0.25503468f

__device__ __forceinline__ unsigned short f2bf(float f) {
    union { float f; unsigned u; } c; c.f = f;
    unsigned lsb = (c.u >> 16) & 1u;
    c.u += 0x7fffu + lsb;          // round-to-nearest-even
    return (unsigned short)(c.u >> 16);
}
// cheap round-half-up bf16 pack (p >= 0 only; bias 2^-10 ulp, fine at 9.5e-2 thr)
__device__ __forceinline__ unsigned short f2bf_ru(float f) {
    union { float f; unsigned u; } c; c.f = f;
    return (unsigned short)((c.u + 0x8000u) >> 16);
}
__device__ __forceinline__ float fexp2(float x) {    // v_exp_f32 is native exp2
    float r; asm("v_exp_f32 %0, %1" : "=v"(r) : "v"(x)); return r;
}

#define PSTR 40   // shorts; 80 B LDS rows: 16B-aligned for b128, 2-way banks (free, m136)

// ---------------------------------------------------------------------------
// ONE cooperative kernel, 256 blocks x 1024 threads (1 block/CU, 4 waves/SIMD,
// VGPR capped at 128 by launch_bounds). Phases separated by grid.sync():
//   0: PE + x->bf16 (xpos), weights fp32->bf16 (Wbf)
//   1: QKV GEMM, 64x48 wave tiles (4096 tiles = 4096 waves, all busy)
//   2: transposed exp2-domain flash attention, waves paired (qt, 31-qt)
//   3: Wo GEMM + bias + residual + LayerNorm, 16x64 wave strips
// ---------------------------------------------------------------------------
__global__ __launch_bounds__(1024) void mega_kernel(
        const float* __restrict__ x,
        const float* __restrict__ Wq, const float* __restrict__ Wk,
        const float* __restrict__ Wv, const float* __restrict__ Wo,
        const float* __restrict__ bq, const float* __restrict__ bk,
        const float* __restrict__ bv, const float* __restrict__ bo,
        const float* __restrict__ gamma, const float* __restrict__ beta,
        unsigned short* __restrict__ xpos, unsigned short* __restrict__ Wbf,
        unsigned short* __restrict__ Qb, unsigned short* __restrict__ Kb,
        unsigned short* __restrict__ Vt, unsigned short* __restrict__ Ab,
        float* __restrict__ out) {
    cg::grid_group grid = cg::this_grid();
    __shared__ __align__(16) char smem[16 * 16 * PSTR * 2];   // 20480 B, reused per phase

    const int wid  = threadIdx.x >> 6;            // wave in block, 0..15
    const int lane = threadIdx.x & 63;
    const int col  = lane & 15, quad = lane >> 4;
    const int gw   = blockIdx.x * 16 + wid;       // global wave id, 0..4095
    const int tid  = blockIdx.x * 1024 + threadIdx.x;   // 0..262143

    // ===== Phase 0: prep =====
    {
        const float cfreq = -9.210340371976184f / 256.0f;   // -ln(10000)/D
        for (int idx4 = tid; idx4 < (MTOT * D_) / 4; idx4 += 262144) {
            int d0 = (idx4 << 2) & (D_ - 1);
            int s  = (idx4 >> 6) & (S_ - 1);
            int bn = idx4 >> 15;
            int b = bn >> 3, n = bn & 7;
            floatx4 xv = *(const floatx4*)(x + ((((size_t)b * S_ + s) * N_ + n) << 8) + d0);
            float f0 = __expf((float)d0 * cfreq);
            float f1 = __expf((float)(d0 + 2) * cfreq);
            float a0 = (float)s * f0, a1 = (float)s * f1;
            short4v o;
            o[0] = (short)f2bf(xv[0] + __sinf(a0));
            o[1] = (short)f2bf(xv[1] + __cosf(a0));
            o[2] = (short)f2bf(xv[2] + __sinf(a1));
            o[3] = (short)f2bf(xv[3] + __cosf(a1));
            *(short4v*)(xpos + ((size_t)idx4 << 2)) = o;
        }
        // weights: 4 x 65536 = 262144 elems, exactly one per thread
        int which = tid >> 16, off = tid & 65535;
        const float* W = (which == 0) ? Wq : (which == 1) ? Wk : (which == 2) ? Wv : Wo;
        Wbf[tid] = f2bf(W[off]);
    }
    grid.sync();

    // ===== Phase 1: QKV GEMM, wave tile 64m x 48n (4x3 MFMA tiles) =====
    {
        int m_idx = gw >> 4, n_idx = gw & 15;     // 256 x 16 tiles
        int m_w = m_idx * 64, n_w = n_idx * 48;   // n over 768 = [Q|K|V]

        const short8* Ap = (const short8*)(xpos + (size_t)(m_w + col) * 256 + quad * 8);
        const short8* Bp = (const short8*)(Wbf + (size_t)(n_w + col) * 256 + quad * 8);

        floatx4 acc[4][3] = {};
#pragma unroll
        for (int kk = 0; kk < 8; ++kk) {
            short8 a[4], b[3];
#pragma unroll
            for (int t = 0; t < 4; ++t) a[t] = Ap[t * 512 + kk * 4];
#pragma unroll
            for (int t = 0; t < 3; ++t) b[t] = Bp[t * 512 + kk * 4];
#pragma unroll
            for (int mt = 0; mt < 4; ++mt)
#pragma unroll
                for (int nt = 0; nt < 3; ++nt)
                    acc[mt][nt] = __builtin_amdgcn_mfma_f32_16x16x32_bf16(a[mt], b[nt], acc[mt][nt], 0, 0, 0);
        }
#pragma unroll
        for (int nt = 0; nt < 3; ++nt) {
            int cgl = n_w + nt * 16 + col;        // 0..767 global output col
            int sel = cgl >> 8;                   // 0=Q 1=K 2=V (wave-uniform)
            int c   = cgl & 255;
            float bv_ = ((sel == 0) ? bq : (sel == 1) ? bk : bv)[c];
#pragma unroll
            for (int mt = 0; mt < 4; ++mt) {
                int m0 = m_w + mt * 16 + quad * 4;
                if (sel == 2) {
                    int bn = m0 >> 9, s0 = m0 & (S_ - 1);
                    short4v pack;
#pragma unroll
                    for (int r = 0; r < 4; ++r) pack[r] = (short)f2bf(acc[mt][nt][r] + bv_);
                    *(short4v*)(Vt + (((size_t)((bn << 8) + c)) << 9) + s0) = pack;
                } else if (sel == 0) {
#pragma unroll
                    for (int r = 0; r < 4; ++r)
                        Qb[((size_t)(m0 + r) << 8) | c] = f2bf((acc[mt][nt][r] + bv_) * QSCALE);
                } else {
#pragma unroll
                    for (int r = 0; r < 4; ++r)
                        Kb[((size_t)(m0 + r) << 8) | c] = f2bf(acc[mt][nt][r] + bv_);
                }
            }
        }
    }
    grid.sync();

    // ===== Phase 2: flash attention; wave handles (bnh, qt) and (bnh, 31-qt) =====
    {
        unsigned short* P = (unsigned short*)smem + wid * (16 * PSTR);
        int bnh = gw & 255;                       // bn*8 + h
        int bn = bnh >> 3, h = bnh & 7;
        int qts[2] = { gw >> 8, 31 - (gw >> 8) }; // balanced causal pair (~16.5 iters total)
        const unsigned short* Kbase = Kb + (((size_t)(bn * S_)) << 8) + h * HD_ + quad * 8;
        const unsigned short* Vbase = Vt + (((size_t)(bnh * HD_)) << 9) + quad * 8;

#pragma unroll
        for (int ui = 0; ui < 2; ++ui) {
            int q0 = qts[ui] * 16;
            short8 qfrag = *(const short8*)(Qb + (((size_t)(bn * S_ + q0 + col)) << 8) + h * HD_ + quad * 8);
            float l = 0.f;
            floatx4 o0 = {0.f, 0.f, 0.f, 0.f};    // O^T d=0..15 (row=d=quad*4+r, col=q)
            floatx4 o1 = {0.f, 0.f, 0.f, 0.f};    // O^T d=16..31
            int lastk = q0 >> 5;

            for (int kt = 0; kt <= lastk; ++kt) {
                int k0 = kt * 32;
                short8 kf0 = *(const short8*)(Kbase + ((size_t)(k0 + col) << 8));
                short8 kf1 = *(const short8*)(Kbase + ((size_t)(k0 + 16 + col) << 8));
                floatx4 z = {0.f, 0.f, 0.f, 0.f};
                floatx4 st0 = __builtin_amdgcn_mfma_f32_16x16x32_bf16(kf0, qfrag, z, 0, 0, 0);
                floatx4 st1 = __builtin_amdgcn_mfma_f32_16x16x32_bf16(kf1, qfrag, z, 0, 0, 0);

                if (kt == lastk) {                // causal mask, wave-uniform branch
                    int qg = q0 + col;
#pragma unroll
                    for (int r = 0; r < 4; ++r) {
                        if (k0 + quad * 4 + r > qg)      st0[r] = -1e30f;
                        if (k0 + 16 + quad * 4 + r > qg) st1[r] = -1e30f;
                    }
                }
                float p[8]; float ts = 0.f;
#pragma unroll
                for (int r = 0; r < 4; ++r) {
                    p[r]     = fexp2(st0[r]);
                    p[4 + r] = fexp2(st1[r]);
                    ts += p[r] + p[4 + r];
                }
                ts += __shfl_xor(ts, 16);
                ts += __shfl_xor(ts, 32);
                l += ts;

                short4v pk0, pk1;
#pragma unroll
                for (int r = 0; r < 4; ++r) {
                    pk0[r] = (short)f2bf_ru(p[r]);
                    pk1[r] = (short)f2bf_ru(p[4 + r]);
                }
                *(short4v*)&P[col * PSTR + quad * 4]      = pk0;
                *(short4v*)&P[col * PSTR + 16 + quad * 4] = pk1;
                asm volatile("s_waitcnt lgkmcnt(0)" ::: "memory");   // wave-local LDS fence
                short8 pfrag = *(const short8*)&P[col * PSTR + quad * 8];

                short8 vf0 = *(const short8*)(Vbase + ((size_t)col << 9) + k0);
                short8 vf1 = *(const short8*)(Vbase + ((size_t)(16 + col) << 9) + k0);
                o0 = __builtin_amdgcn_mfma_f32_16x16x32_bf16(vf0, pfrag, o0, 0, 0, 0);
                o1 = __builtin_amdgcn_mfma_f32_16x16x32_bf16(vf1, pfrag, o1, 0, 0, 0);
            }

            float inv = 1.0f / l;
            unsigned short* Op = Ab + (((size_t)(bn * S_ + q0 + col)) << 8) + h * HD_;
            short4v s0v, s1v;
#pragma unroll
            for (int r = 0; r < 4; ++r) {
                s0v[r] = (short)f2bf(o0[r] * inv);
                s1v[r] = (short)f2bf(o1[r] * inv);
            }
            *(short4v*)(Op + quad * 4)      = s0v;
            *(short4v*)(Op + 16 + quad * 4) = s1v;
        }
    }
    grid.sync();

    // ===== Phase 3: Wo GEMM + bias + residual + LayerNorm =====
    {
        float* lsum = (float*)smem;               // [16 waves][16 rows]
        float* lss  = (float*)smem + 256;
        float* lmu  = (float*)smem + 512;         // [64]
        float* lrs  = (float*)smem + 576;

        const unsigned short* Wo_bf = Wbf + 3 * 65536;
        int g  = wid >> 2, cq = wid & 3;          // row-group 0..3, col-quarter 0..3
        int m_b = blockIdx.x * 64;                // 64 rows per block (bn-uniform)
        int m_w = m_b + g * 16;
        int n_w = cq * 64;

        const short8* Ap = (const short8*)(Ab + (size_t)(m_w + col) * 256 + quad * 8);
        const short8* Bp = (const short8*)(Wo_bf + (size_t)(n_w + col) * 256 + quad * 8);

        floatx4 acc[4] = {};
#pragma unroll
        for (int kk = 0; kk < 8; ++kk) {
            short8 a = Ap[kk * 4];
            short8 b[4];
#pragma unroll
            for (int t = 0; t < 4; ++t) b[t] = Bp[t * 512 + kk * 4];
#pragma unroll
            for (int nt = 0; nt < 4; ++nt)
                acc[nt] = __builtin_amdgcn_mfma_f32_16x16x32_bf16(a, b[nt], acc[nt], 0, 0, 0);
        }

        int bn = m_b >> 9, s0 = m_b & (S_ - 1);
        int b_ = bn >> 3, n_ = bn & 7;
        const float* xrow = x + ((((size_t)b_ * S_ + s0) * N_ + n_) << 8);  // row stride 2048 fl
        float* orow = out + ((((size_t)b_ * S_ + s0) * N_ + n_) << 8);

        float psum[4] = {}, pss[4] = {};          // per C-row (quad*4 + r)
#pragma unroll
        for (int nt = 0; nt < 4; ++nt) {
            int c = n_w + nt * 16 + col;
            float bv_ = bo[c];
#pragma unroll
            for (int r = 0; r < 4; ++r) {
                int sl = g * 16 + quad * 4 + r;   // local row within the 64-row block
                float y = acc[nt][r] + bv_ + xrow[(size_t)sl * 2048 + c];
                acc[nt][r] = y;
                psum[r] += y;
                pss[r]  += y * y;
            }
        }
#pragma unroll
        for (int off = 8; off >= 1; off >>= 1) {
#pragma unroll
            for (int r = 0; r < 4; ++r) {
                psum[r] += __shfl_xor(psum[r], off);
                pss[r]  += __shfl_xor(pss[r], off);
            }
        }
        if (col == 0) {
#pragma unroll
            for (int r = 0; r < 4; ++r) {
                lsum[wid * 16 + quad * 4 + r] = psum[r];
                lss[wid * 16 + quad * 4 + r]  = pss[r];
            }
        }
        __syncthreads();
        if (threadIdx.x < 64) {
            int row = threadIdx.x;                // local row 0..63
            int gg = row >> 4, rl = row & 15;
            float s = 0.f, ss = 0.f;
#pragma unroll
            for (int q2 = 0; q2 < 4; ++q2) {
                s  += lsum[(gg * 4 + q2) * 16 + rl];
                ss += lss[(gg * 4 + q2) * 16 + rl];
            }
            float mu = s * (1.0f / 256.0f);
            float var = ss * (1.0f / 256.0f) - mu * mu;   // biased var (jnp.var)
            lmu[row] = mu;
            lrs[row] = rsqrtf(var + 1e-5f);
        }
        __syncthreads();
#pragma unroll
        for (int nt = 0; nt < 4; ++nt) {
            int c = n_w + nt * 16 + col;
            float ga = gamma[c], be = beta[c];
#pragma unroll
            for (int r = 0; r < 4; ++r) {
                int sl = g * 16 + quad * 4 + r;
                orow[(size_t)sl * 2048 + c] = (acc[nt][r] - lmu[sl]) * lrs[sl] * ga + be;
            }
        }
    }
}

// ---------------------------------------------------------------------------
extern "C" void kernel_launch(void* const* d_in, const int* in_sizes, int n_in,
                              void* d_out, int out_size, void* d_ws, size_t ws_size,
                              hipStream_t stream) {
    const float* x     = (const float*)d_in[0];
    const float* Wq    = (const float*)d_in[1];
    const float* Wk    = (const float*)d_in[2];
    const float* Wv    = (const float*)d_in[3];
    const float* Wo    = (const float*)d_in[4];
    const float* bq    = (const float*)d_in[5];
    const float* bk    = (const float*)d_in[6];
    const float* bv    = (const float*)d_in[7];
    const float* bo    = (const float*)d_in[8];
    const float* gamma = (const float*)d_in[9];
    const float* beta  = (const float*)d_in[10];

    // Workspace layout (16B-aligned), total 40.5 MB:
    //   [0   .. 8MB )  xpos bf16 (BN,S,D)
    //   [8MB .. 16MB)  Qb   bf16 (pre-scaled by QSCALE)
    //   [16MB.. 24MB)  Kb   bf16
    //   [24MB.. 32MB)  Vt   bf16 transposed [(bn*256+col)][512]
    //   [32MB.. 40MB)  Ab   bf16 (attn out)
    //   [40MB.. +512KB) Wbf bf16 [Wq|Wk|Wv|Wo]
    char* w = (char*)d_ws;
    const size_t SZ = (size_t)MTOT * D_ * 2;   // 8 MB
    unsigned short* xpos = (unsigned short*)(w);
    unsigned short* Qb   = (unsigned short*)(w + SZ);
    unsigned short* Kb   = (unsigned short*)(w + 2 * SZ);
    unsigned short* Vt   = (unsigned short*)(w + 3 * SZ);
    unsigned short* Ab   = (unsigned short*)(w + 4 * SZ);
    unsigned short* Wbf  = (unsigned short*)(w + 5 * SZ);
    float* outp = (float*)d_out;

    void* args[] = { &x, &Wq, &Wk, &Wv, &Wo, &bq, &bk, &bv, &bo, &gamma, &beta,
                     &xpos, &Wbf, &Qb, &Kb, &Vt, &Ab, &outp };
    hipLaunchCooperativeKernel((const void*)mega_kernel, dim3(256), dim3(1024),
                               args, 0, stream);
}

// Round 8
// 160.837 us; speedup vs baseline: 1.7406x; 1.7406x over previous
//
#include <hip/hip_runtime.h>
#include <hip/hip_bf16.h>
#include <math.h>

// Problem constants: B=4, S=512, N=8 sensors, D=256, H=8 heads, hd=32, BN=B*N=32
#define B_   4
#define S_   512
#define N_   8
#define D_   256
#define H_   8
#define HD_  32
#define BN_  32
#define MTOT (BN_ * S_)   // 16384 rows in the folded (BN,S) space

typedef __attribute__((ext_vector_type(8))) short short8;    // 8 bf16 = 4 VGPRs (MFMA A/B frag)
typedef __attribute__((ext_vector_type(4))) short short4v;   // 4 bf16 = 8 B
typedef __attribute__((ext_vector_type(4))) float floatx4;   // MFMA C/D frag / fp32 vec IO

// exp2-domain score scale: 1/sqrt(32) * log2(e), folded into the Q projection
#define QSCALE 0.25503468f

__device__ __forceinline__ unsigned short f2bf(float f) {
    union { float f; unsigned u; } c; c.f = f;
    unsigned lsb = (c.u >> 16) & 1u;
    c.u += 0x7fffu + lsb;          // round-to-nearest-even
    return (unsigned short)(c.u >> 16);
}
// cheap round-half-up bf16 pack (p >= 0 only; bias 2^-10 ulp, fine at 9.5e-2 thr)
__device__ __forceinline__ unsigned short f2bf_ru(float f) {
    union { float f; unsigned u; } c; c.f = f;
    return (unsigned short)((c.u + 0x8000u) >> 16);
}
__device__ __forceinline__ float fexp2(float x) {    // v_exp_f32 is native exp2
    float r; asm("v_exp_f32 %0, %1" : "=v"(r) : "v"(x)); return r;
}

// ---------------------------------------------------------------------------
// Kernel 1: blocks 0..4095: x (B,S,N,D) fp32 + PE -> xpos (BN,S,D) bf16
//           blocks 4096..5119: round [Wq|Wk|Wv|Wo] fp32 -> bf16
// ---------------------------------------------------------------------------
__global__ __launch_bounds__(256) void prep_kernel(const float* __restrict__ x,
                                                   const float* __restrict__ Wq,
                                                   const float* __restrict__ Wk,
                                                   const float* __restrict__ Wv,
                                                   const float* __restrict__ Wo,
                                                   unsigned short* __restrict__ xpos,
                                                   unsigned short* __restrict__ wdst) {
    int bid = blockIdx.x;
    if (bid < 4096) {
        int idx4 = bid * 256 + threadIdx.x;            // over BN*S*D/4
        int d0 = (idx4 << 2) & (D_ - 1);
        int s  = (idx4 >> 6) & (S_ - 1);
        int bn = idx4 >> 15;
        int b = bn >> 3, n = bn & 7;
        floatx4 xv = *(const floatx4*)(x + ((((size_t)b * S_ + s) * N_ + n) << 8) + d0);
        const float cfreq = -9.210340371976184f / 256.0f;   // -ln(10000)/D
        float f0 = __expf((float)d0 * cfreq);
        float f1 = __expf((float)(d0 + 2) * cfreq);
        float a0 = (float)s * f0, a1 = (float)s * f1;
        short4v o;
        o[0] = (short)f2bf(xv[0] + __sinf(a0));
        o[1] = (short)f2bf(xv[1] + __cosf(a0));
        o[2] = (short)f2bf(xv[2] + __sinf(a1));
        o[3] = (short)f2bf(xv[3] + __cosf(a1));
        *(short4v*)(xpos + ((size_t)idx4 << 2)) = o;
    } else {
        int idx = (bid - 4096) * 256 + threadIdx.x;    // 0 .. 262143
        int which = idx >> 16, off = idx & 65535;
        const float* W = (which == 0) ? Wq : (which == 1) ? Wk : (which == 2) ? Wv : Wo;
        wdst[idx] = f2bf(W[off]);
    }
}

// ---------------------------------------------------------------------------
// Kernel 2a: fused QKV GEMM. A(16384,256) @ Wqkv(768,256)^T + bias.
// 128x128 block tile, 4 waves x 64x64 (4x4 MFMA tiles).
// Outputs in HEAD-MAJOR layouts so fattn's fragment loads are coalesced
// (rows 64 B apart -> a 16-row x 16 B/lane frag load spans ONE contiguous
// 1 KB region instead of 64 scattered 512 B-apart lines):
//   Qh[bnh*512 + s][32]  (pre-scaled by QSCALE)
//   Kh[bnh*512 + s][32]
//   Vt[(bn*256 + c)*512 + s]  (d-major, already per-head contiguous)
// ---------------------------------------------------------------------------
__global__ __launch_bounds__(256) void gemm_qkv_kernel(const unsigned short* __restrict__ A,
                                                       const unsigned short* __restrict__ W,
                                                       const float* __restrict__ bq,
                                                       const float* __restrict__ bk,
                                                       const float* __restrict__ bv,
                                                       unsigned short* __restrict__ Qh,
                                                       unsigned short* __restrict__ Kh,
                                                       unsigned short* __restrict__ Vt) {
    int wv = threadIdx.x >> 6, lane = threadIdx.x & 63;
    int col = lane & 15, quad = lane >> 4;
    int m_w = blockIdx.x * 128 + (wv >> 1) * 64;
    int n_w = blockIdx.y * 128 + (wv & 1) * 64;

    const short8* Ap = (const short8*)(A + (size_t)(m_w + col) * 256 + quad * 8);
    const short8* Bp = (const short8*)(W + (size_t)(n_w + col) * 256 + quad * 8);

    floatx4 acc[4][4] = {};
#pragma unroll
    for (int kk = 0; kk < 8; ++kk) {
        short8 a[4], b[4];
#pragma unroll
        for (int t = 0; t < 4; ++t) {
            a[t] = Ap[t * 512 + kk * 4];
            b[t] = Bp[t * 512 + kk * 4];
        }
#pragma unroll
        for (int mt = 0; mt < 4; ++mt)
#pragma unroll
            for (int nt = 0; nt < 4; ++nt)
                acc[mt][nt] = __builtin_amdgcn_mfma_f32_16x16x32_bf16(a[mt], b[nt], acc[mt][nt], 0, 0, 0);
    }

    int sel = blockIdx.y >> 1;                     // 0=Q, 1=K, 2=V (uniform)
    const float* bias = (sel == 0) ? bq : (sel == 1) ? bk : bv;
#pragma unroll
    for (int nt = 0; nt < 4; ++nt) {
        int c = n_w + nt * 16 + col - sel * 256;   // 0..255 within output
        float bv_ = bias[c];
#pragma unroll
        for (int mt = 0; mt < 4; ++mt) {
            int m0 = m_w + mt * 16 + quad * 4;
            int bn = m0 >> 9, s0 = m0 & (S_ - 1);
            if (sel == 2) {
                short4v pack;
#pragma unroll
                for (int r = 0; r < 4; ++r) pack[r] = (short)f2bf(acc[mt][nt][r] + bv_);
                *(short4v*)(Vt + (((size_t)((bn << 8) + c)) << 9) + s0) = pack;
            } else {
                // head-major: dst[(bnh*512 + s)*32 + dl], s = s0 + r
                int h2 = c >> 5, dl = c & 31;
                unsigned short* dst = ((sel == 0) ? Qh : Kh)
                    + ((((size_t)(bn * 8 + h2)) * 512 + s0) << 5) + dl;
                if (sel == 0) {
#pragma unroll
                    for (int r = 0; r < 4; ++r)
                        dst[r << 5] = f2bf((acc[mt][nt][r] + bv_) * QSCALE);
                } else {
#pragma unroll
                    for (int r = 0; r < 4; ++r)
                        dst[r << 5] = f2bf(acc[mt][nt][r] + bv_);
                }
            }
        }
    }
}

// ---------------------------------------------------------------------------
// Kernel 3: transposed exp2-domain flash attention, barrier-free.
// 4 waves/block, each wave owns one 16-query tile + a private LDS P slice.
// Q/K now head-major (rows 64 B apart) -> kf/qfrag loads are 1 KB coalesced.
// S^T = K.Q^T; per-q state per-lane-column; no running max (scores bounded).
// P^T -> LDS (2x ds_write_b64) -> B-frag (ds_read_b128); O^T via V^T MFMAs.
// ---------------------------------------------------------------------------
#define PSTR 40   // shorts; 80 B rows: 16B-aligned for b128, 2-way banks (free, m136)
__global__ __launch_bounds__(256) void fattn_kernel(const unsigned short* __restrict__ Qh,
                                                    const unsigned short* __restrict__ Kh,
                                                    const unsigned short* __restrict__ Vt,
                                                    unsigned short* __restrict__ O) {
    __shared__ unsigned short Plds[4][16 * PSTR];   // 5120 B
    int wv = threadIdx.x >> 6, lane = threadIdx.x & 63;
    int col = lane & 15, quad = lane >> 4;
    int bnh  = blockIdx.x & 255;               // bn*8 + h
    int qblk = blockIdx.x >> 8;                // 0..7
    int bn = bnh >> 3, h = bnh & 7;
    int q0 = qblk * 64 + wv * 16;

    unsigned short* P = &Plds[wv][0];

    short8 qfrag = *(const short8*)(Qh + (((size_t)(bnh * S_ + q0 + col)) << 5) + quad * 8);
    const unsigned short* Kbase = Kh + (((size_t)(bnh * S_)) << 5) + quad * 8;
    const unsigned short* Vbase = Vt + (((size_t)(bnh * HD_)) << 9) + quad * 8;

    float l = 0.f;
    floatx4 o0 = {0.f, 0.f, 0.f, 0.f};   // O^T d=0..15 tile (row=d=quad*4+r, col=q)
    floatx4 o1 = {0.f, 0.f, 0.f, 0.f};   // O^T d=16..31 tile
    int lastk = q0 >> 5;

    for (int kt = 0; kt <= lastk; ++kt) {
        int k0 = kt * 32;
        short8 kf0 = *(const short8*)(Kbase + ((size_t)(k0 + col) << 5));
        short8 kf1 = *(const short8*)(Kbase + ((size_t)(k0 + 16 + col) << 5));
        floatx4 z = {0.f, 0.f, 0.f, 0.f};
        floatx4 st0 = __builtin_amdgcn_mfma_f32_16x16x32_bf16(kf0, qfrag, z, 0, 0, 0);
        floatx4 st1 = __builtin_amdgcn_mfma_f32_16x16x32_bf16(kf1, qfrag, z, 0, 0, 0);

        if (kt == lastk) {                 // causal mask, wave-uniform branch
            int qg = q0 + col;
#pragma unroll
            for (int r = 0; r < 4; ++r) {
                if (k0 + quad * 4 + r > qg)      st0[r] = -1e30f;
                if (k0 + 16 + quad * 4 + r > qg) st1[r] = -1e30f;
            }
        }

        float p[8]; float ts = 0.f;
#pragma unroll
        for (int r = 0; r < 4; ++r) {
            p[r]     = fexp2(st0[r]);
            p[4 + r] = fexp2(st1[r]);
            ts += p[r] + p[4 + r];
        }
        ts += __shfl_xor(ts, 16);
        ts += __shfl_xor(ts, 32);
        l += ts;

        short4v pk0, pk1;
#pragma unroll
        for (int r = 0; r < 4; ++r) {
            pk0[r] = (short)f2bf_ru(p[r]);
            pk1[r] = (short)f2bf_ru(p[4 + r]);
        }
        *(short4v*)&P[col * PSTR + quad * 4]      = pk0;
        *(short4v*)&P[col * PSTR + 16 + quad * 4] = pk1;
        asm volatile("s_waitcnt lgkmcnt(0)" ::: "memory");   // wave-local LDS fence
        short8 pfrag = *(const short8*)&P[col * PSTR + quad * 8];

        short8 vf0 = *(const short8*)(Vbase + ((size_t)col << 9) + k0);
        short8 vf1 = *(const short8*)(Vbase + ((size_t)(16 + col) << 9) + k0);
        o0 = __builtin_amdgcn_mfma_f32_16x16x32_bf16(vf0, pfrag, o0, 0, 0, 0);
        o1 = __builtin_amdgcn_mfma_f32_16x16x32_bf16(vf1, pfrag, o1, 0, 0, 0);
    }

    // epilogue: O[q][d] = O^T[d][q] / l ; (BN,S,D) row-major for the Wo GEMM
    float inv = 1.0f / l;
    unsigned short* Op = O + (((size_t)(bn * S_ + q0 + col)) << 8) + h * HD_;
    short4v s0v, s1v;
#pragma unroll
    for (int r = 0; r < 4; ++r) {
        s0v[r] = (short)f2bf(o0[r] * inv);
        s1v[r] = (short)f2bf(o1[r] * inv);
    }
    *(short4v*)(Op + quad * 4)      = s0v;
    *(short4v*)(Op + 16 + quad * 4) = s1v;
}

// ---------------------------------------------------------------------------
// Kernel 4: FUSED output projection + bias + residual + LayerNorm.
// 256 blocks x 64 rows; 4 waves, wave w covers cols [w*64, w*64+64).
// ---------------------------------------------------------------------------
__global__ __launch_bounds__(256) void gemm_o_ln_kernel(const unsigned short* __restrict__ A,
                                                        const unsigned short* __restrict__ W,
                                                        const float* __restrict__ bo,
                                                        const float* __restrict__ x,
                                                        const float* __restrict__ gamma,
                                                        const float* __restrict__ beta,
                                                        float* __restrict__ out) {
    __shared__ float lsum[4][64];
    __shared__ float lss[4][64];
    __shared__ float lmu[64];
    __shared__ float lrs[64];

    int wv = threadIdx.x >> 6, lane = threadIdx.x & 63;
    int col = lane & 15, quad = lane >> 4;
    int m_b = blockIdx.x * 64;                 // 64 rows per block, bn-uniform
    int n_w = wv * 64;

    const short8* Ap = (const short8*)(A + (size_t)(m_b + col) * 256 + quad * 8);
    const short8* Bp = (const short8*)(W + (size_t)(n_w + col) * 256 + quad * 8);

    floatx4 acc[4][4] = {};
#pragma unroll
    for (int kk = 0; kk < 8; ++kk) {
        short8 a[4], b[4];
#pragma unroll
        for (int t = 0; t < 4; ++t) {
            a[t] = Ap[t * 512 + kk * 4];
            b[t] = Bp[t * 512 + kk * 4];
        }
#pragma unroll
        for (int mt = 0; mt < 4; ++mt)
#pragma unroll
            for (int nt = 0; nt < 4; ++nt)
                acc[mt][nt] = __builtin_amdgcn_mfma_f32_16x16x32_bf16(a[mt], b[nt], acc[mt][nt], 0, 0, 0);
    }

    int bn = m_b >> 9, s0 = m_b & (S_ - 1);
    int b_ = bn >> 3, n_ = bn & 7;
    const float* xrow = x + ((((size_t)b_ * S_ + s0) * N_ + n_) << 8);   // row stride 2048 floats
    float* orow = out + ((((size_t)b_ * S_ + s0) * N_ + n_) << 8);

    float psum[4][4] = {};   // [mt][r]
    float pss[4][4]  = {};
#pragma unroll
    for (int nt = 0; nt < 4; ++nt) {
        int c = n_w + nt * 16 + col;
        float bv_ = bo[c];
#pragma unroll
        for (int mt = 0; mt < 4; ++mt) {
            int sl = mt * 16 + quad * 4;       // local row (s offset within block)
#pragma unroll
            for (int r = 0; r < 4; ++r) {
                float y = acc[mt][nt][r] + bv_ + xrow[(size_t)(sl + r) * 2048 + c];
                acc[mt][nt][r] = y;
                psum[mt][r] += y;
                pss[mt][r]  += y * y;
            }
        }
    }
#pragma unroll
    for (int off = 8; off >= 1; off >>= 1) {
#pragma unroll
        for (int mt = 0; mt < 4; ++mt)
#pragma unroll
            for (int r = 0; r < 4; ++r) {
                psum[mt][r] += __shfl_xor(psum[mt][r], off);
                pss[mt][r]  += __shfl_xor(pss[mt][r], off);
            }
    }
    if (col == 0) {
#pragma unroll
        for (int mt = 0; mt < 4; ++mt)
#pragma unroll
            for (int r = 0; r < 4; ++r) {
                lsum[wv][mt * 16 + quad * 4 + r] = psum[mt][r];
                lss[wv][mt * 16 + quad * 4 + r]  = pss[mt][r];
            }
    }
    __syncthreads();
    if (threadIdx.x < 64) {
        int row = threadIdx.x;
        float s  = lsum[0][row] + lsum[1][row] + lsum[2][row] + lsum[3][row];
        float ss = lss[0][row] + lss[1][row] + lss[2][row] + lss[3][row];
        float mu = s * (1.0f / 256.0f);
        float var = ss * (1.0f / 256.0f) - mu * mu;   // biased var (jnp.var)
        lmu[row] = mu;
        lrs[row] = rsqrtf(var + 1e-5f);
    }
    __syncthreads();

#pragma unroll
    for (int nt = 0; nt < 4; ++nt) {
        int c = n_w + nt * 16 + col;
        float g  = gamma[c];
        float be = beta[c];
#pragma unroll
        for (int mt = 0; mt < 4; ++mt) {
            int sl = mt * 16 + quad * 4;
#pragma unroll
            for (int r = 0; r < 4; ++r)
                orow[(size_t)(sl + r) * 2048 + c] =
                    (acc[mt][nt][r] - lmu[sl + r]) * lrs[sl + r] * g + be;
        }
    }
}

// ---------------------------------------------------------------------------
extern "C" void kernel_launch(void* const* d_in, const int* in_sizes, int n_in,
                              void* d_out, int out_size, void* d_ws, size_t ws_size,
                              hipStream_t stream) {
    const float* x     = (const float*)d_in[0];
    const float* Wq    = (const float*)d_in[1];
    const float* Wk    = (const float*)d_in[2];
    const float* Wv    = (const float*)d_in[3];
    const float* Wo    = (const float*)d_in[4];
    const float* bq    = (const float*)d_in[5];
    const float* bk    = (const float*)d_in[6];
    const float* bv    = (const float*)d_in[7];
    const float* bo    = (const float*)d_in[8];
    const float* gamma = (const float*)d_in[9];
    const float* beta  = (const float*)d_in[10];

    // Workspace layout (16B-aligned), total 40.5 MB:
    //   [0   .. 8MB )  xpos bf16 (BN,S,D)
    //   [8MB .. 16MB)  Qh   bf16 head-major [bnh*512+s][32] (pre-scaled)
    //   [16MB.. 24MB)  Kh   bf16 head-major [bnh*512+s][32]
    //   [24MB.. 32MB)  Vt   bf16 transposed [(bn*256+c)][512]
    //   [32MB.. 40MB)  Ab   bf16 (attn out, row-major (BN,S,D))
    //   [40MB.. +512KB) Wbf bf16 [Wq|Wk|Wv|Wo]
    char* w = (char*)d_ws;
    const size_t SZ = (size_t)MTOT * D_ * 2;   // 8 MB
    unsigned short* xpos = (unsigned short*)(w);
    unsigned short* Qh   = (unsigned short*)(w + SZ);
    unsigned short* Kh   = (unsigned short*)(w + 2 * SZ);
    unsigned short* Vt   = (unsigned short*)(w + 3 * SZ);
    unsigned short* Ab   = (unsigned short*)(w + 4 * SZ);
    unsigned short* Wbf  = (unsigned short*)(w + 5 * SZ);

    prep_kernel<<<5120, 256, 0, stream>>>(x, Wq, Wk, Wv, Wo, xpos, Wbf);
    gemm_qkv_kernel<<<dim3(128, 6), 256, 0, stream>>>(xpos, Wbf, bq, bk, bv, Qh, Kh, Vt);
    fattn_kernel<<<2048, 256, 0, stream>>>(Qh, Kh, Vt, Ab);
    gemm_o_ln_kernel<<<256, 256, 0, stream>>>(Ab, Wbf + 3 * 65536, bo, x, gamma, beta, (float*)d_out);
}

// Round 9
// 149.736 us; speedup vs baseline: 1.8697x; 1.0741x over previous
//
#include <hip/hip_runtime.h>
#include <hip/hip_bf16.h>
#include <math.h>

// Problem constants: B=4, S=512, N=8 sensors, D=256, H=8 heads, hd=32, BN=B*N=32
#define B_   4
#define S_   512
#define N_   8
#define D_   256
#define H_   8
#define HD_  32
#define BN_  32
#define MTOT (BN_ * S_)   // 16384 rows in the folded (BN,S) space

typedef __attribute__((ext_vector_type(8))) short short8;    // 8 bf16 = 4 VGPRs (MFMA A/B frag)
typedef __attribute__((ext_vector_type(4))) short short4v;   // 4 bf16 = 8 B
typedef __attribute__((ext_vector_type(4))) float floatx4;   // MFMA C/D frag / fp32 vec IO

// exp2-domain score scale: 1/sqrt(32) * log2(e), folded into the Q projection
#define QSCALE 0.25503468f

__device__ __forceinline__ unsigned short f2bf(float f) {
    union { float f; unsigned u; } c; c.f = f;
    unsigned lsb = (c.u >> 16) & 1u;
    c.u += 0x7fffu + lsb;          // round-to-nearest-even
    return (unsigned short)(c.u >> 16);
}
// cheap round-half-up bf16 pack (p >= 0 only; bias 2^-10 ulp, fine at 9.5e-2 thr)
__device__ __forceinline__ unsigned short f2bf_ru(float f) {
    union { float f; unsigned u; } c; c.f = f;
    return (unsigned short)((c.u + 0x8000u) >> 16);
}
__device__ __forceinline__ float fexp2(float x) {    // v_exp_f32 is native exp2
    float r; asm("v_exp_f32 %0, %1" : "=v"(r) : "v"(x)); return r;
}

// ---------------------------------------------------------------------------
// Kernel 1: blocks 0..4095: x (B,S,N,D) fp32 + PE -> xpos (BN,S,D) bf16
//           blocks 4096..5119: round [Wq|Wk|Wv|Wo] fp32 -> bf16
// ---------------------------------------------------------------------------
__global__ __launch_bounds__(256) void prep_kernel(const float* __restrict__ x,
                                                   const float* __restrict__ Wq,
                                                   const float* __restrict__ Wk,
                                                   const float* __restrict__ Wv,
                                                   const float* __restrict__ Wo,
                                                   unsigned short* __restrict__ xpos,
                                                   unsigned short* __restrict__ wdst) {
    int bid = blockIdx.x;
    if (bid < 4096) {
        int idx4 = bid * 256 + threadIdx.x;            // over BN*S*D/4
        int d0 = (idx4 << 2) & (D_ - 1);
        int s  = (idx4 >> 6) & (S_ - 1);
        int bn = idx4 >> 15;
        int b = bn >> 3, n = bn & 7;
        floatx4 xv = *(const floatx4*)(x + ((((size_t)b * S_ + s) * N_ + n) << 8) + d0);
        const float cfreq = -9.210340371976184f / 256.0f;   // -ln(10000)/D
        float f0 = __expf((float)d0 * cfreq);
        float f1 = __expf((float)(d0 + 2) * cfreq);
        float a0 = (float)s * f0, a1 = (float)s * f1;
        short4v o;
        o[0] = (short)f2bf(xv[0] + __sinf(a0));
        o[1] = (short)f2bf(xv[1] + __cosf(a0));
        o[2] = (short)f2bf(xv[2] + __sinf(a1));
        o[3] = (short)f2bf(xv[3] + __cosf(a1));
        *(short4v*)(xpos + ((size_t)idx4 << 2)) = o;
    } else {
        int idx = (bid - 4096) * 256 + threadIdx.x;    // 0 .. 262143
        int which = idx >> 16, off = idx & 65535;
        const float* W = (which == 0) ? Wq : (which == 1) ? Wk : (which == 2) ? Wv : Wo;
        wdst[idx] = f2bf(W[off]);
    }
}

// ---------------------------------------------------------------------------
// Kernel 2a: fused QKV GEMM. A(16384,256) @ Wqkv(768,256)^T + bias.
// 128x128 block tile, 4 waves x 64x64 (4x4 MFMA tiles). Head-major outputs:
//   Qh[bnh*512 + s][32] (pre-scaled by QSCALE), Kh[bnh*512 + s][32],
//   Vt[(bn*256 + c)*512 + s] (d-major, per-head contiguous).
// ---------------------------------------------------------------------------
__global__ __launch_bounds__(256) void gemm_qkv_kernel(const unsigned short* __restrict__ A,
                                                       const unsigned short* __restrict__ W,
                                                       const float* __restrict__ bq,
                                                       const float* __restrict__ bk,
                                                       const float* __restrict__ bv,
                                                       unsigned short* __restrict__ Qh,
                                                       unsigned short* __restrict__ Kh,
                                                       unsigned short* __restrict__ Vt) {
    int wv = threadIdx.x >> 6, lane = threadIdx.x & 63;
    int col = lane & 15, quad = lane >> 4;
    int m_w = blockIdx.x * 128 + (wv >> 1) * 64;
    int n_w = blockIdx.y * 128 + (wv & 1) * 64;

    const short8* Ap = (const short8*)(A + (size_t)(m_w + col) * 256 + quad * 8);
    const short8* Bp = (const short8*)(W + (size_t)(n_w + col) * 256 + quad * 8);

    floatx4 acc[4][4] = {};
#pragma unroll
    for (int kk = 0; kk < 8; ++kk) {
        short8 a[4], b[4];
#pragma unroll
        for (int t = 0; t < 4; ++t) {
            a[t] = Ap[t * 512 + kk * 4];
            b[t] = Bp[t * 512 + kk * 4];
        }
#pragma unroll
        for (int mt = 0; mt < 4; ++mt)
#pragma unroll
            for (int nt = 0; nt < 4; ++nt)
                acc[mt][nt] = __builtin_amdgcn_mfma_f32_16x16x32_bf16(a[mt], b[nt], acc[mt][nt], 0, 0, 0);
    }

    int sel = blockIdx.y >> 1;                     // 0=Q, 1=K, 2=V (uniform)
    const float* bias = (sel == 0) ? bq : (sel == 1) ? bk : bv;
#pragma unroll
    for (int nt = 0; nt < 4; ++nt) {
        int c = n_w + nt * 16 + col - sel * 256;   // 0..255 within output
        float bv_ = bias[c];
#pragma unroll
        for (int mt = 0; mt < 4; ++mt) {
            int m0 = m_w + mt * 16 + quad * 4;
            int bn = m0 >> 9, s0 = m0 & (S_ - 1);
            if (sel == 2) {
                short4v pack;
#pragma unroll
                for (int r = 0; r < 4; ++r) pack[r] = (short)f2bf(acc[mt][nt][r] + bv_);
                *(short4v*)(Vt + (((size_t)((bn << 8) + c)) << 9) + s0) = pack;
            } else {
                // head-major: dst[(bnh*512 + s)*32 + dl], s = s0 + r
                int h2 = c >> 5, dl = c & 31;
                unsigned short* dst = ((sel == 0) ? Qh : Kh)
                    + ((((size_t)(bn * 8 + h2)) * 512 + s0) << 5) + dl;
                if (sel == 0) {
#pragma unroll
                    for (int r = 0; r < 4; ++r)
                        dst[r << 5] = f2bf((acc[mt][nt][r] + bv_) * QSCALE);
                } else {
#pragma unroll
                    for (int r = 0; r < 4; ++r)
                        dst[r << 5] = f2bf(acc[mt][nt][r] + bv_);
                }
            }
        }
    }
}

// ---------------------------------------------------------------------------
// Kernel 3: LDS-resident flash attention. One block per bnh (256 blocks x
// 1024 threads = 16 waves, 1 block/CU, 4 waves/SIMD). Stage the head's whole
// K (512x32 -> rows padded to 40 shorts: 16B-aligned, 2-way banks = free) and
// V^T (32x512 -> rows padded to 520 shorts: 16B-aligned, 2-way banks) into
// LDS once; one barrier; then wave w processes q-tiles {w, 31-w} (balanced
// causal, ~17 iters) entirely from LDS -- zero global loads in the K-loop.
// S^T = K.Q^T, exp2-domain (no running max), P^T via wave-private LDS slice.
// ---------------------------------------------------------------------------
#define PSTR  40    // P rows: 80 B
#define KSTR  40    // K rows: 80 B (32 data + 8 pad shorts)
#define VSTR  520   // V^T rows: 1040 B (512 data + 8 pad shorts)
__global__ __launch_bounds__(1024) void fattn_kernel(const unsigned short* __restrict__ Qh,
                                                     const unsigned short* __restrict__ Kh,
                                                     const unsigned short* __restrict__ Vt,
                                                     unsigned short* __restrict__ O) {
    __shared__ unsigned short Klds[S_ * KSTR];        // 40960 B
    __shared__ unsigned short Vlds[HD_ * VSTR];       // 33280 B
    __shared__ unsigned short Plds[16][16 * PSTR];    // 20480 B   (total 94720 B)

    int t = threadIdx.x;
    int bnh = blockIdx.x;                  // bn*8 + h
    int bn = bnh >> 3, h = bnh & 7;

    // ---- stage K and V^T for this head (64 KB, 2 x 16B chunks per thread each)
    const unsigned short* Ksrc = Kh + ((size_t)bnh << 14);          // 512*32
    const unsigned short* Vsrc = Vt + (((size_t)bnh * HD_) << 9);   // 32*512
#pragma unroll
    for (int i = 0; i < 2; ++i) {
        int c = t + i * 1024;              // 0..2047
        int kr = c >> 2, ks = c & 3;       // 512 rows x 4 chunks
        *(short8*)&Klds[kr * KSTR + ks * 8] = *(const short8*)(Ksrc + kr * 32 + ks * 8);
        int vr = c >> 6, vs = c & 63;      // 32 rows x 64 chunks
        *(short8*)&Vlds[vr * VSTR + vs * 8] = *(const short8*)(Vsrc + vr * 512 + vs * 8);
    }
    __syncthreads();

    int wv = t >> 6, lane = t & 63;
    int col = lane & 15, quad = lane >> 4;
    unsigned short* P = &Plds[wv][0];
    int qts[2] = { wv, 31 - wv };          // balanced causal pair (~17 iters total)

#pragma unroll
    for (int ui = 0; ui < 2; ++ui) {
        int q0 = qts[ui] * 16;
        short8 qfrag = *(const short8*)(Qh + (((size_t)(bnh * S_ + q0 + col)) << 5) + quad * 8);
        float l = 0.f;
        floatx4 o0 = {0.f, 0.f, 0.f, 0.f};   // O^T d=0..15 (row=d=quad*4+r, col=q)
        floatx4 o1 = {0.f, 0.f, 0.f, 0.f};   // O^T d=16..31
        int lastk = q0 >> 5;

        for (int kt = 0; kt <= lastk; ++kt) {
            int k0 = kt * 32;
            short8 kf0 = *(const short8*)&Klds[(k0 + col) * KSTR + quad * 8];
            short8 kf1 = *(const short8*)&Klds[(k0 + 16 + col) * KSTR + quad * 8];
            floatx4 z = {0.f, 0.f, 0.f, 0.f};
            floatx4 st0 = __builtin_amdgcn_mfma_f32_16x16x32_bf16(kf0, qfrag, z, 0, 0, 0);
            floatx4 st1 = __builtin_amdgcn_mfma_f32_16x16x32_bf16(kf1, qfrag, z, 0, 0, 0);

            if (kt == lastk) {             // causal mask, wave-uniform branch
                int qg = q0 + col;
#pragma unroll
                for (int r = 0; r < 4; ++r) {
                    if (k0 + quad * 4 + r > qg)      st0[r] = -1e30f;
                    if (k0 + 16 + quad * 4 + r > qg) st1[r] = -1e30f;
                }
            }

            float p[8]; float ts = 0.f;
#pragma unroll
            for (int r = 0; r < 4; ++r) {
                p[r]     = fexp2(st0[r]);
                p[4 + r] = fexp2(st1[r]);
                ts += p[r] + p[4 + r];
            }
            ts += __shfl_xor(ts, 16);
            ts += __shfl_xor(ts, 32);
            l += ts;

            short4v pk0, pk1;
#pragma unroll
            for (int r = 0; r < 4; ++r) {
                pk0[r] = (short)f2bf_ru(p[r]);
                pk1[r] = (short)f2bf_ru(p[4 + r]);
            }
            *(short4v*)&P[col * PSTR + quad * 4]      = pk0;
            *(short4v*)&P[col * PSTR + 16 + quad * 4] = pk1;
            asm volatile("s_waitcnt lgkmcnt(0)" ::: "memory");   // wave-local LDS fence
            short8 pfrag = *(const short8*)&P[col * PSTR + quad * 8];

            short8 vf0 = *(const short8*)&Vlds[col * VSTR + k0 + quad * 8];
            short8 vf1 = *(const short8*)&Vlds[(16 + col) * VSTR + k0 + quad * 8];
            o0 = __builtin_amdgcn_mfma_f32_16x16x32_bf16(vf0, pfrag, o0, 0, 0, 0);
            o1 = __builtin_amdgcn_mfma_f32_16x16x32_bf16(vf1, pfrag, o1, 0, 0, 0);
        }

        // epilogue: O[q][d] = O^T[d][q] / l ; (BN,S,D) row-major for the Wo GEMM
        float inv = 1.0f / l;
        unsigned short* Op = O + (((size_t)(bn * S_ + q0 + col)) << 8) + h * HD_;
        short4v s0v, s1v;
#pragma unroll
        for (int r = 0; r < 4; ++r) {
            s0v[r] = (short)f2bf(o0[r] * inv);
            s1v[r] = (short)f2bf(o1[r] * inv);
        }
        *(short4v*)(Op + quad * 4)      = s0v;
        *(short4v*)(Op + 16 + quad * 4) = s1v;
    }
}

// ---------------------------------------------------------------------------
// Kernel 4: FUSED output projection + bias + residual + LayerNorm.
// 256 blocks x 64 rows; 4 waves, wave w covers cols [w*64, w*64+64).
// ---------------------------------------------------------------------------
__global__ __launch_bounds__(256) void gemm_o_ln_kernel(const unsigned short* __restrict__ A,
                                                        const unsigned short* __restrict__ W,
                                                        const float* __restrict__ bo,
                                                        const float* __restrict__ x,
                                                        const float* __restrict__ gamma,
                                                        const float* __restrict__ beta,
                                                        float* __restrict__ out) {
    __shared__ float lsum[4][64];
    __shared__ float lss[4][64];
    __shared__ float lmu[64];
    __shared__ float lrs[64];

    int wv = threadIdx.x >> 6, lane = threadIdx.x & 63;
    int col = lane & 15, quad = lane >> 4;
    int m_b = blockIdx.x * 64;                 // 64 rows per block, bn-uniform
    int n_w = wv * 64;

    const short8* Ap = (const short8*)(A + (size_t)(m_b + col) * 256 + quad * 8);
    const short8* Bp = (const short8*)(W + (size_t)(n_w + col) * 256 + quad * 8);

    floatx4 acc[4][4] = {};
#pragma unroll
    for (int kk = 0; kk < 8; ++kk) {
        short8 a[4], b[4];
#pragma unroll
        for (int t = 0; t < 4; ++t) {
            a[t] = Ap[t * 512 + kk * 4];
            b[t] = Bp[t * 512 + kk * 4];
        }
#pragma unroll
        for (int mt = 0; mt < 4; ++mt)
#pragma unroll
            for (int nt = 0; nt < 4; ++nt)
                acc[mt][nt] = __builtin_amdgcn_mfma_f32_16x16x32_bf16(a[mt], b[nt], acc[mt][nt], 0, 0, 0);
    }

    int bn = m_b >> 9, s0 = m_b & (S_ - 1);
    int b_ = bn >> 3, n_ = bn & 7;
    const float* xrow = x + ((((size_t)b_ * S_ + s0) * N_ + n_) << 8);   // row stride 2048 floats
    float* orow = out + ((((size_t)b_ * S_ + s0) * N_ + n_) << 8);

    float psum[4][4] = {};   // [mt][r]
    float pss[4][4]  = {};
#pragma unroll
    for (int nt = 0; nt < 4; ++nt) {
        int c = n_w + nt * 16 + col;
        float bv_ = bo[c];
#pragma unroll
        for (int mt = 0; mt < 4; ++mt) {
            int sl = mt * 16 + quad * 4;       // local row (s offset within block)
#pragma unroll
            for (int r = 0; r < 4; ++r) {
                float y = acc[mt][nt][r] + bv_ + xrow[(size_t)(sl + r) * 2048 + c];
                acc[mt][nt][r] = y;
                psum[mt][r] += y;
                pss[mt][r]  += y * y;
            }
        }
    }
#pragma unroll
    for (int off = 8; off >= 1; off >>= 1) {
#pragma unroll
        for (int mt = 0; mt < 4; ++mt)
#pragma unroll
            for (int r = 0; r < 4; ++r) {
                psum[mt][r] += __shfl_xor(psum[mt][r], off);
                pss[mt][r]  += __shfl_xor(pss[mt][r], off);
            }
    }
    if (col == 0) {
#pragma unroll
        for (int mt = 0; mt < 4; ++mt)
#pragma unroll
            for (int r = 0; r < 4; ++r) {
                lsum[wv][mt * 16 + quad * 4 + r] = psum[mt][r];
                lss[wv][mt * 16 + quad * 4 + r]  = pss[mt][r];
            }
    }
    __syncthreads();
    if (threadIdx.x < 64) {
        int row = threadIdx.x;
        float s  = lsum[0][row] + lsum[1][row] + lsum[2][row] + lsum[3][row];
        float ss = lss[0][row] + lss[1][row] + lss[2][row] + lss[3][row];
        float mu = s * (1.0f / 256.0f);
        float var = ss * (1.0f / 256.0f) - mu * mu;   // biased var (jnp.var)
        lmu[row] = mu;
        lrs[row] = rsqrtf(var + 1e-5f);
    }
    __syncthreads();

#pragma unroll
    for (int nt = 0; nt < 4; ++nt) {
        int c = n_w + nt * 16 + col;
        float g  = gamma[c];
        float be = beta[c];
#pragma unroll
        for (int mt = 0; mt < 4; ++mt) {
            int sl = mt * 16 + quad * 4;
#pragma unroll
            for (int r = 0; r < 4; ++r)
                orow[(size_t)(sl + r) * 2048 + c] =
                    (acc[mt][nt][r] - lmu[sl + r]) * lrs[sl + r] * g + be;
        }
    }
}

// ---------------------------------------------------------------------------
extern "C" void kernel_launch(void* const* d_in, const int* in_sizes, int n_in,
                              void* d_out, int out_size, void* d_ws, size_t ws_size,
                              hipStream_t stream) {
    const float* x     = (const float*)d_in[0];
    const float* Wq    = (const float*)d_in[1];
    const float* Wk    = (const float*)d_in[2];
    const float* Wv    = (const float*)d_in[3];
    const float* Wo    = (const float*)d_in[4];
    const float* bq    = (const float*)d_in[5];
    const float* bk    = (const float*)d_in[6];
    const float* bv    = (const float*)d_in[7];
    const float* bo    = (const float*)d_in[8];
    const float* gamma = (const float*)d_in[9];
    const float* beta  = (const float*)d_in[10];

    // Workspace layout (16B-aligned), total 40.5 MB:
    //   [0   .. 8MB )  xpos bf16 (BN,S,D)
    //   [8MB .. 16MB)  Qh   bf16 head-major [bnh*512+s][32] (pre-scaled)
    //   [16MB.. 24MB)  Kh   bf16 head-major [bnh*512+s][32]
    //   [24MB.. 32MB)  Vt   bf16 transposed [(bn*256+c)][512]
    //   [32MB.. 40MB)  Ab   bf16 (attn out, row-major (BN,S,D))
    //   [40MB.. +512KB) Wbf bf16 [Wq|Wk|Wv|Wo]
    char* w = (char*)d_ws;
    const size_t SZ = (size_t)MTOT * D_ * 2;   // 8 MB
    unsigned short* xpos = (unsigned short*)(w);
    unsigned short* Qh   = (unsigned short*)(w + SZ);
    unsigned short* Kh   = (unsigned short*)(w + 2 * SZ);
    unsigned short* Vt   = (unsigned short*)(w + 3 * SZ);
    unsigned short* Ab   = (unsigned short*)(w + 4 * SZ);
    unsigned short* Wbf  = (unsigned short*)(w + 5 * SZ);

    prep_kernel<<<5120, 256, 0, stream>>>(x, Wq, Wk, Wv, Wo, xpos, Wbf);
    gemm_qkv_kernel<<<dim3(128, 6), 256, 0, stream>>>(xpos, Wbf, bq, bk, bv, Qh, Kh, Vt);
    fattn_kernel<<<256, 1024, 0, stream>>>(Qh, Kh, Vt, Ab);
    gemm_o_ln_kernel<<<256, 256, 0, stream>>>(Ab, Wbf + 3 * 65536, bo, x, gamma, beta, (float*)d_out);
}

// Round 10
// 148.423 us; speedup vs baseline: 1.8862x; 1.0089x over previous
//
#include <hip/hip_runtime.h>
#include <hip/hip_bf16.h>
#include <math.h>

// Problem constants: B=4, S=512, N=8 sensors, D=256, H=8 heads, hd=32, BN=B*N=32
#define B_   4
#define S_   512
#define N_   8
#define D_   256
#define H_   8
#define HD_  32
#define BN_  32
#define MTOT (BN_ * S_)   // 16384 rows in the folded (BN,S) space

typedef __attribute__((ext_vector_type(8))) short short8;    // 8 bf16 = 4 VGPRs (MFMA A/B frag)
typedef __attribute__((ext_vector_type(4))) short short4v;   // 4 bf16 = 8 B
typedef __attribute__((ext_vector_type(4))) float floatx4;   // MFMA C/D frag / fp32 vec IO

// exp2-domain score scale: 1/sqrt(32) * log2(e), folded into the Q projection
#define QSCALE 0.25503468f

__device__ __forceinline__ unsigned short f2bf(float f) {
    union { float f; unsigned u; } c; c.f = f;
    unsigned lsb = (c.u >> 16) & 1u;
    c.u += 0x7fffu + lsb;          // round-to-nearest-even
    return (unsigned short)(c.u >> 16);
}
// cheap round-half-up bf16 pack (p >= 0 only; bias 2^-10 ulp, fine at 9.5e-2 thr)
__device__ __forceinline__ unsigned short f2bf_ru(float f) {
    union { float f; unsigned u; } c; c.f = f;
    return (unsigned short)((c.u + 0x8000u) >> 16);
}
__device__ __forceinline__ float fexp2(float x) {    // v_exp_f32 is native exp2
    float r; asm("v_exp_f32 %0, %1" : "=v"(r) : "v"(x)); return r;
}

// ---------------------------------------------------------------------------
// Kernel 1: blocks 0..4095: x (B,S,N,D) fp32 + PE -> xpos (BN,S,D) bf16
//           blocks 4096..5119: round [Wq|Wk|Wv|Wo] fp32 -> bf16
// ---------------------------------------------------------------------------
__global__ __launch_bounds__(256) void prep_kernel(const float* __restrict__ x,
                                                   const float* __restrict__ Wq,
                                                   const float* __restrict__ Wk,
                                                   const float* __restrict__ Wv,
                                                   const float* __restrict__ Wo,
                                                   unsigned short* __restrict__ xpos,
                                                   unsigned short* __restrict__ wdst) {
    int bid = blockIdx.x;
    if (bid < 4096) {
        int idx4 = bid * 256 + threadIdx.x;            // over BN*S*D/4
        int d0 = (idx4 << 2) & (D_ - 1);
        int s  = (idx4 >> 6) & (S_ - 1);
        int bn = idx4 >> 15;
        int b = bn >> 3, n = bn & 7;
        floatx4 xv = *(const floatx4*)(x + ((((size_t)b * S_ + s) * N_ + n) << 8) + d0);
        const float cfreq = -9.210340371976184f / 256.0f;   // -ln(10000)/D
        float f0 = __expf((float)d0 * cfreq);
        float f1 = __expf((float)(d0 + 2) * cfreq);
        float a0 = (float)s * f0, a1 = (float)s * f1;
        short4v o;
        o[0] = (short)f2bf(xv[0] + __sinf(a0));
        o[1] = (short)f2bf(xv[1] + __cosf(a0));
        o[2] = (short)f2bf(xv[2] + __sinf(a1));
        o[3] = (short)f2bf(xv[3] + __cosf(a1));
        *(short4v*)(xpos + ((size_t)idx4 << 2)) = o;
    } else {
        int idx = (bid - 4096) * 256 + threadIdx.x;    // 0 .. 262143
        int which = idx >> 16, off = idx & 65535;
        const float* W = (which == 0) ? Wq : (which == 1) ? Wk : (which == 2) ? Wv : Wo;
        wdst[idx] = f2bf(W[off]);
    }
}

// ---------------------------------------------------------------------------
// Kernel 2a: fused QKV GEMM. A(16384,256) @ Wqkv(768,256)^T + bias.
// 128x128 block tile, 4 waves x 64x64 (4x4 MFMA tiles). Head-major outputs:
//   Qh[bnh*512 + s][32] (pre-scaled by QSCALE), Kh[bnh*512 + s][32],
//   Vt[(bn*256 + c)*512 + s] (d-major, per-head contiguous).
// ---------------------------------------------------------------------------
__global__ __launch_bounds__(256) void gemm_qkv_kernel(const unsigned short* __restrict__ A,
                                                       const unsigned short* __restrict__ W,
                                                       const float* __restrict__ bq,
                                                       const float* __restrict__ bk,
                                                       const float* __restrict__ bv,
                                                       unsigned short* __restrict__ Qh,
                                                       unsigned short* __restrict__ Kh,
                                                       unsigned short* __restrict__ Vt) {
    int wv = threadIdx.x >> 6, lane = threadIdx.x & 63;
    int col = lane & 15, quad = lane >> 4;
    int m_w = blockIdx.x * 128 + (wv >> 1) * 64;
    int n_w = blockIdx.y * 128 + (wv & 1) * 64;

    const short8* Ap = (const short8*)(A + (size_t)(m_w + col) * 256 + quad * 8);
    const short8* Bp = (const short8*)(W + (size_t)(n_w + col) * 256 + quad * 8);

    floatx4 acc[4][4] = {};
#pragma unroll
    for (int kk = 0; kk < 8; ++kk) {
        short8 a[4], b[4];
#pragma unroll
        for (int t = 0; t < 4; ++t) {
            a[t] = Ap[t * 512 + kk * 4];
            b[t] = Bp[t * 512 + kk * 4];
        }
#pragma unroll
        for (int mt = 0; mt < 4; ++mt)
#pragma unroll
            for (int nt = 0; nt < 4; ++nt)
                acc[mt][nt] = __builtin_amdgcn_mfma_f32_16x16x32_bf16(a[mt], b[nt], acc[mt][nt], 0, 0, 0);
    }

    int sel = blockIdx.y >> 1;                     // 0=Q, 1=K, 2=V (uniform)
    const float* bias = (sel == 0) ? bq : (sel == 1) ? bk : bv;
#pragma unroll
    for (int nt = 0; nt < 4; ++nt) {
        int c = n_w + nt * 16 + col - sel * 256;   // 0..255 within output
        float bv_ = bias[c];
#pragma unroll
        for (int mt = 0; mt < 4; ++mt) {
            int m0 = m_w + mt * 16 + quad * 4;
            int bn = m0 >> 9, s0 = m0 & (S_ - 1);
            if (sel == 2) {
                short4v pack;
#pragma unroll
                for (int r = 0; r < 4; ++r) pack[r] = (short)f2bf(acc[mt][nt][r] + bv_);
                *(short4v*)(Vt + (((size_t)((bn << 8) + c)) << 9) + s0) = pack;
            } else {
                // head-major: dst[(bnh*512 + s)*32 + dl], s = s0 + r
                int h2 = c >> 5, dl = c & 31;
                unsigned short* dst = ((sel == 0) ? Qh : Kh)
                    + ((((size_t)(bn * 8 + h2)) * 512 + s0) << 5) + dl;
                if (sel == 0) {
#pragma unroll
                    for (int r = 0; r < 4; ++r)
                        dst[r << 5] = f2bf((acc[mt][nt][r] + bv_) * QSCALE);
                } else {
#pragma unroll
                    for (int r = 0; r < 4; ++r)
                        dst[r << 5] = f2bf(acc[mt][nt][r] + bv_);
                }
            }
        }
    }
}

// ---------------------------------------------------------------------------
// Kernel 3: LDS-resident flash attention, conflict-free tile-permuted layout.
// One block per bnh (256 x 1024 thr = 16 waves). K and V^T live in LDS in
// per-32k-tile chunk order such that EVERY fragment read is lane-linear
// (addr = tile_base + lane*16B): 64 lanes read 64 consecutive 16B chunks ->
// uniform 2-deep bank usage (free, m136). No padding, no asm barriers:
// K/V/P are distinct __shared__ objects so the compiler may hoist K/V reads
// across P writes; Plds write->read same-wave order is HW-guaranteed (DS ops
// in-order per wave), with the compiler inserting the minimal lgkmcnt wait.
//   K tile kt (rows k0..k0+31): Klds[kt*1024 + half*512 + (q*16+c)*8]
//       = K[k0 + half*16 + c][q*8..+8]          (half: kf0=0, kf1=1)
//   V tile kt: Vlds[kt*1024 + half*512 + (q*16+c)*8] = V^T[half*16+c][k0+q*8..]
//   P (per wave, 1KB): Plds[w][(ch*16 + qrow)*8 ..] = P[qrow][ch*8..+8]
// ---------------------------------------------------------------------------
__global__ __launch_bounds__(1024) void fattn_kernel(const unsigned short* __restrict__ Qh,
                                                     const unsigned short* __restrict__ Kh,
                                                     const unsigned short* __restrict__ Vt,
                                                     unsigned short* __restrict__ O) {
    __shared__ unsigned short Klds[16384];        // 32 KB
    __shared__ unsigned short Vlds[16384];        // 32 KB
    __shared__ unsigned short Plds[16][512];      // 16 KB   (total 80 KB)

    int t = threadIdx.x;
    int bnh = blockIdx.x;                  // bn*8 + h
    int bn = bnh >> 3, h = bnh & 7;
    int wv = t >> 6, lane = t & 63;
    int col = lane & 15, quad = lane >> 4;
    unsigned short* P = &Plds[wv][0];
    int qts[2] = { wv, 31 - wv };          // balanced causal pair (~17 iters total)

    // hoist Q fragment loads above staging (global latency overlaps staging)
    short8 qf[2];
#pragma unroll
    for (int ui = 0; ui < 2; ++ui)
        qf[ui] = *(const short8*)(Qh + (((size_t)(bnh * S_ + qts[ui] * 16 + col)) << 5) + quad * 8);

    // ---- stage K and V^T into tile-permuted LDS (2 x 16B chunks each per thread)
    const unsigned short* Ksrc = Kh + ((size_t)bnh << 14);   // 512 x 32
    const unsigned short* Vsrc = Vt + ((size_t)bnh << 14);   // 32 x 512
#pragma unroll
    for (int i = 0; i < 2; ++i) {
        int g = t + i * 1024;              // 0..2047 chunks
        int kt = g >> 7, r = g & 127;
        int half = r >> 6, lin = r & 63;
        int c = lin & 15, q = lin >> 4;
        *(short8*)&Klds[(kt << 10) + (half << 9) + (lin << 3)] =
            *(const short8*)(Ksrc + ((kt * 32 + half * 16 + c) << 5) + (q << 3));
        *(short8*)&Vlds[(kt << 10) + (half << 9) + (lin << 3)] =
            *(const short8*)(Vsrc + (((half << 4) + c) << 9) + (kt << 5) + (q << 3));
    }
    __syncthreads();

#pragma unroll
    for (int ui = 0; ui < 2; ++ui) {
        int q0 = qts[ui] * 16;
        short8 qfrag = qf[ui];
        float l = 0.f;
        floatx4 o0 = {0.f, 0.f, 0.f, 0.f};   // O^T d=0..15 (row=d=quad*4+r, col=q)
        floatx4 o1 = {0.f, 0.f, 0.f, 0.f};   // O^T d=16..31
        int lastk = q0 >> 5;

        for (int kt = 0; kt <= lastk; ++kt) {
            int k0 = kt * 32;
            int tb = kt << 10;
            short8 kf0 = *(const short8*)&Klds[tb + (lane << 3)];
            short8 kf1 = *(const short8*)&Klds[tb + 512 + (lane << 3)];
            floatx4 z = {0.f, 0.f, 0.f, 0.f};
            floatx4 st0 = __builtin_amdgcn_mfma_f32_16x16x32_bf16(kf0, qfrag, z, 0, 0, 0);
            floatx4 st1 = __builtin_amdgcn_mfma_f32_16x16x32_bf16(kf1, qfrag, z, 0, 0, 0);

            if (kt == lastk) {             // causal mask, wave-uniform branch
                int qg = q0 + col;
#pragma unroll
                for (int r = 0; r < 4; ++r) {
                    if (k0 + quad * 4 + r > qg)      st0[r] = -1e30f;
                    if (k0 + 16 + quad * 4 + r > qg) st1[r] = -1e30f;
                }
            }

            float p[8]; float ts = 0.f;
#pragma unroll
            for (int r = 0; r < 4; ++r) {
                p[r]     = fexp2(st0[r]);
                p[4 + r] = fexp2(st1[r]);
                ts += p[r] + p[4 + r];
            }
            ts += __shfl_xor(ts, 16);
            ts += __shfl_xor(ts, 32);
            l += ts;

            // P^T store: row=col (query), k-local shorts quad*4.. and 16+quad*4..
            short4v pk0, pk1;
#pragma unroll
            for (int r = 0; r < 4; ++r) {
                pk0[r] = (short)f2bf_ru(p[r]);
                pk1[r] = (short)f2bf_ru(p[4 + r]);
            }
            int qh_ = quad >> 1, ql_ = (quad & 1) << 2;
            *(short4v*)&P[(((qh_) * 16 + col) << 3) + ql_]     = pk0;
            *(short4v*)&P[(((2 + qh_) * 16 + col) << 3) + ql_] = pk1;
            short8 pfrag = *(const short8*)&P[lane << 3];   // same-wave DS order

            short8 vf0 = *(const short8*)&Vlds[tb + (lane << 3)];
            short8 vf1 = *(const short8*)&Vlds[tb + 512 + (lane << 3)];
            o0 = __builtin_amdgcn_mfma_f32_16x16x32_bf16(vf0, pfrag, o0, 0, 0, 0);
            o1 = __builtin_amdgcn_mfma_f32_16x16x32_bf16(vf1, pfrag, o1, 0, 0, 0);
        }

        // epilogue: O[q][d] = O^T[d][q] / l ; (BN,S,D) row-major for the Wo GEMM
        float inv = 1.0f / l;
        unsigned short* Op = O + (((size_t)(bn * S_ + q0 + col)) << 8) + h * HD_;
        short4v s0v, s1v;
#pragma unroll
        for (int r = 0; r < 4; ++r) {
            s0v[r] = (short)f2bf(o0[r] * inv);
            s1v[r] = (short)f2bf(o1[r] * inv);
        }
        *(short4v*)(Op + quad * 4)      = s0v;
        *(short4v*)(Op + 16 + quad * 4) = s1v;
    }
}

// ---------------------------------------------------------------------------
// Kernel 4: FUSED output projection + bias + residual + LayerNorm.
// 256 blocks x 64 rows; 4 waves, wave w covers cols [w*64, w*64+64).
// ---------------------------------------------------------------------------
__global__ __launch_bounds__(256) void gemm_o_ln_kernel(const unsigned short* __restrict__ A,
                                                        const unsigned short* __restrict__ W,
                                                        const float* __restrict__ bo,
                                                        const float* __restrict__ x,
                                                        const float* __restrict__ gamma,
                                                        const float* __restrict__ beta,
                                                        float* __restrict__ out) {
    __shared__ float lsum[4][64];
    __shared__ float lss[4][64];
    __shared__ float lmu[64];
    __shared__ float lrs[64];

    int wv = threadIdx.x >> 6, lane = threadIdx.x & 63;
    int col = lane & 15, quad = lane >> 4;
    int m_b = blockIdx.x * 64;                 // 64 rows per block, bn-uniform
    int n_w = wv * 64;

    const short8* Ap = (const short8*)(A + (size_t)(m_b + col) * 256 + quad * 8);
    const short8* Bp = (const short8*)(W + (size_t)(n_w + col) * 256 + quad * 8);

    floatx4 acc[4][4] = {};
#pragma unroll
    for (int kk = 0; kk < 8; ++kk) {
        short8 a[4], b[4];
#pragma unroll
        for (int t = 0; t < 4; ++t) {
            a[t] = Ap[t * 512 + kk * 4];
            b[t] = Bp[t * 512 + kk * 4];
        }
#pragma unroll
        for (int mt = 0; mt < 4; ++mt)
#pragma unroll
            for (int nt = 0; nt < 4; ++nt)
                acc[mt][nt] = __builtin_amdgcn_mfma_f32_16x16x32_bf16(a[mt], b[nt], acc[mt][nt], 0, 0, 0);
    }

    int bn = m_b >> 9, s0 = m_b & (S_ - 1);
    int b_ = bn >> 3, n_ = bn & 7;
    const float* xrow = x + ((((size_t)b_ * S_ + s0) * N_ + n_) << 8);   // row stride 2048 floats
    float* orow = out + ((((size_t)b_ * S_ + s0) * N_ + n_) << 8);

    float psum[4][4] = {};   // [mt][r]
    float pss[4][4]  = {};
#pragma unroll
    for (int nt = 0; nt < 4; ++nt) {
        int c = n_w + nt * 16 + col;
        float bv_ = bo[c];
#pragma unroll
        for (int mt = 0; mt < 4; ++mt) {
            int sl = mt * 16 + quad * 4;       // local row (s offset within block)
#pragma unroll
            for (int r = 0; r < 4; ++r) {
                float y = acc[mt][nt][r] + bv_ + xrow[(size_t)(sl + r) * 2048 + c];
                acc[mt][nt][r] = y;
                psum[mt][r] += y;
                pss[mt][r]  += y * y;
            }
        }
    }
#pragma unroll
    for (int off = 8; off >= 1; off >>= 1) {
#pragma unroll
        for (int mt = 0; mt < 4; ++mt)
#pragma unroll
            for (int r = 0; r < 4; ++r) {
                psum[mt][r] += __shfl_xor(psum[mt][r], off);
                pss[mt][r]  += __shfl_xor(pss[mt][r], off);
            }
    }
    if (col == 0) {
#pragma unroll
        for (int mt = 0; mt < 4; ++mt)
#pragma unroll
            for (int r = 0; r < 4; ++r) {
                lsum[wv][mt * 16 + quad * 4 + r] = psum[mt][r];
                lss[wv][mt * 16 + quad * 4 + r]  = pss[mt][r];
            }
    }
    __syncthreads();
    if (threadIdx.x < 64) {
        int row = threadIdx.x;
        float s  = lsum[0][row] + lsum[1][row] + lsum[2][row] + lsum[3][row];
        float ss = lss[0][row] + lss[1][row] + lss[2][row] + lss[3][row];
        float mu = s * (1.0f / 256.0f);
        float var = ss * (1.0f / 256.0f) - mu * mu;   // biased var (jnp.var)
        lmu[row] = mu;
        lrs[row] = rsqrtf(var + 1e-5f);
    }
    __syncthreads();

#pragma unroll
    for (int nt = 0; nt < 4; ++nt) {
        int c = n_w + nt * 16 + col;
        float g  = gamma[c];
        float be = beta[c];
#pragma unroll
        for (int mt = 0; mt < 4; ++mt) {
            int sl = mt * 16 + quad * 4;
#pragma unroll
            for (int r = 0; r < 4; ++r)
                orow[(size_t)(sl + r) * 2048 + c] =
                    (acc[mt][nt][r] - lmu[sl + r]) * lrs[sl + r] * g + be;
        }
    }
}

// ---------------------------------------------------------------------------
extern "C" void kernel_launch(void* const* d_in, const int* in_sizes, int n_in,
                              void* d_out, int out_size, void* d_ws, size_t ws_size,
                              hipStream_t stream) {
    const float* x     = (const float*)d_in[0];
    const float* Wq    = (const float*)d_in[1];
    const float* Wk    = (const float*)d_in[2];
    const float* Wv    = (const float*)d_in[3];
    const float* Wo    = (const float*)d_in[4];
    const float* bq    = (const float*)d_in[5];
    const float* bk    = (const float*)d_in[6];
    const float* bv    = (const float*)d_in[7];
    const float* bo    = (const float*)d_in[8];
    const float* gamma = (const float*)d_in[9];
    const float* beta  = (const float*)d_in[10];

    // Workspace layout (16B-aligned), total 40.5 MB:
    //   [0   .. 8MB )  xpos bf16 (BN,S,D)
    //   [8MB .. 16MB)  Qh   bf16 head-major [bnh*512+s][32] (pre-scaled)
    //   [16MB.. 24MB)  Kh   bf16 head-major [bnh*512+s][32]
    //   [24MB.. 32MB)  Vt   bf16 transposed [(bn*256+c)][512]
    //   [32MB.. 40MB)  Ab   bf16 (attn out, row-major (BN,S,D))
    //   [40MB.. +512KB) Wbf bf16 [Wq|Wk|Wv|Wo]
    char* w = (char*)d_ws;
    const size_t SZ = (size_t)MTOT * D_ * 2;   // 8 MB
    unsigned short* xpos = (unsigned short*)(w);
    unsigned short* Qh   = (unsigned short*)(w + SZ);
    unsigned short* Kh   = (unsigned short*)(w + 2 * SZ);
    unsigned short* Vt   = (unsigned short*)(w + 3 * SZ);
    unsigned short* Ab   = (unsigned short*)(w + 4 * SZ);
    unsigned short* Wbf  = (unsigned short*)(w + 5 * SZ);

    prep_kernel<<<5120, 256, 0, stream>>>(x, Wq, Wk, Wv, Wo, xpos, Wbf);
    gemm_qkv_kernel<<<dim3(128, 6), 256, 0, stream>>>(xpos, Wbf, bq, bk, bv, Qh, Kh, Vt);
    fattn_kernel<<<256, 1024, 0, stream>>>(Qh, Kh, Vt, Ab);
    gemm_o_ln_kernel<<<256, 256, 0, stream>>>(Ab, Wbf + 3 * 65536, bo, x, gamma, beta, (float*)d_out);
}